// Round 6
// baseline (795.175 us; speedup 1.0000x reference)
//
#include <hip/hip_runtime.h>
#include <math.h>

#define NQ 16
#define NLAYERS 3
#define NSTATES 65536   // 2^16
#define BATCH 256

// Clamped global read: any harness/size mismatch becomes a wrong value,
// never an OOB fault.
__device__ __forceinline__ float rd(const float* __restrict__ p, int i, int n) {
    return p[i < n ? i : (n - 1)];
}

// ---------------------------------------------------------------------------
// One block (1024 threads) per batch element. State index = j*1024 + tid
// (j = register index 0..63).
//   bits 0..5   = lane bits     -> __shfl_xor
//   bits 6..9   = wave bits     -> LDS exchange (32 KiB, 8 chunks of 8 regs)
//   bits 10..15 = register bits -> in-register butterflies
// amdgpu_waves_per_eu(4,4): pin occupancy to 4 waves/EU so the register
// allocator budgets 512/4 = 128 VGPRs. R4/R5 evidence: naked (1024) AND
// (1024,4) both produced VGPR_Count=64 -> full state spill -> 3.19 GB HBM
// scratch traffic, 750 us. The 64-float state MUST stay in registers.
// Output: dense float32 REAL parts (imag==0; all gate matrices real).
// ---------------------------------------------------------------------------
__global__ __launch_bounds__(1024)
__attribute__((amdgpu_waves_per_eu(4, 4)))
void qsim(const float* __restrict__ x,
          const float* __restrict__ rot,
          const float* __restrict__ ent,
          const float* __restrict__ W1,
          const float* __restrict__ b1,
          const float* __restrict__ W2,
          const float* __restrict__ b2,
          float* __restrict__ out,
          long long out_floats,
          int nx, int nrot, int nent, int nW1, int nb1, int nW2, int nb2) {
    const int tid = threadIdx.x;
    const int b   = blockIdx.x;

    __shared__ float  lds[8 * 1024];           // 32 KiB exchange buffer
    __shared__ float4 Mg[NLAYERS * NQ];        // 48 gate matrices
    __shared__ float  pg[NLAYERS * (NQ - 1)];  // 45 CNOT mix probs
    __shared__ float  hidS[64];
    __shared__ float  hqS[16];

    // ---- Phase A: MLP hidden layer (64 threads) + sigmoid probs ----
    if (tid < 64) {
        float s = rd(b1, tid, nb1);
        for (int k = 0; k < 100; k++)
            s = fmaf(rd(x, b * 100 + k, nx), rd(W1, k * 64 + tid, nW1), s);
        hidS[tid] = fmaxf(s, 0.f);
    } else if (tid >= 64 && tid < 64 + NLAYERS * (NQ - 1)) {
        int i = tid - 64;
        pg[i] = 1.f / (1.f + expf(-rd(ent, i, nent)));
    }
    __syncthreads();

    // ---- Phase B: output layer hq (16 threads) ----
    if (tid < 16) {
        float s = rd(b2, tid, nb2);
#pragma unroll 64
        for (int i = 0; i < 64; i++)
            s = fmaf(hidS[i], rd(W2, i * 16 + tid, nW2), s);
        hqS[tid] = tanhf(s);
    }
    __syncthreads();

    // ---- Phase C: gate matrices (48 threads) ----
    if (tid < NLAYERS * NQ) {
        int q = tid & 15;
        float hv = hqS[q];
        float a0 = 0.5f * rd(rot, tid * 3 + 0, nrot) * hv;
        float a1 = 0.5f * rd(rot, tid * 3 + 1, nrot) * hv;
        float a2 = 0.5f * rd(rot, tid * 3 + 2, nrot) * hv;
        float cx = cosf(a0), sx = sinf(a0);
        float cy = cosf(a1), sy = sinf(a1);
        float cz = cosf(a2), sz = sinf(a2);
        Mg[tid] = make_float4(cx * cy * cz, -(sx * sy * sz),
                              sx * sy * cz,  cx * cy * sz);
    }
    __syncthreads();

    // ---- statevector init: |0...0> ----
    float a[64];
#pragma unroll 64
    for (int j = 0; j < 64; j++) a[j] = 0.f;
    if (tid == 0) a[0] = 1.f;

    for (int l = 0; l < NLAYERS; l++) {
        // ---------------- single-qubit gates ----------------
        // q = 0..5 : lane bits (shfl, compile-time masks)
#pragma unroll 6
        for (int q = 0; q < 6; q++) {
            float4 m = Mg[l * NQ + q];
            int bit = (tid >> q) & 1;
            float cown  = bit ? m.w : m.x;
            float cpart = bit ? m.z : m.y;
#pragma unroll 64
            for (int j = 0; j < 64; j++) {
                float part = __shfl_xor(a[j], 1 << q);
                a[j] = cown * a[j] + cpart * part;
            }
        }
        // q = 6..9 : wave bits (LDS exchange, 8 chunks x 8 regs)
#pragma unroll 4
        for (int q = 6; q < 10; q++) {
            float4 m = Mg[l * NQ + q];
            int bit = (tid >> q) & 1;
            float cown  = bit ? m.w : m.x;
            float cpart = bit ? m.z : m.y;
            int partner = tid ^ (1 << q);
#pragma unroll 8
            for (int c = 0; c < 8; c++) {
                __syncthreads();
#pragma unroll 8
                for (int k = 0; k < 8; k++) lds[k * 1024 + tid] = a[c * 8 + k];
                __syncthreads();
#pragma unroll 8
                for (int k = 0; k < 8; k++) {
                    float part = lds[k * 1024 + partner];
                    a[c * 8 + k] = cown * a[c * 8 + k] + cpart * part;
                }
            }
        }
        // q = 10..15 : register bits (in-register butterfly)
#pragma unroll 6
        for (int qq = 0; qq < 6; qq++) {
            float4 m = Mg[l * NQ + 10 + qq];
            const int h = 1 << qq;
#pragma unroll 64
            for (int j = 0; j < 64; j++) {
                if (!(j & h)) {
                    int j1 = j | h;
                    float a0 = a[j], a1 = a[j1];
                    a[j]  = m.x * a0 + m.y * a1;
                    a[j1] = m.z * a0 + m.w * a1;
                }
            }
        }

        // ---------------- noisy CNOTs: ctrl=q, tgt=q+1 ----------------
        // q = 0..4 : ctrl + tgt both lane bits (shfl on tgt)
#pragma unroll 5
        for (int q = 0; q < 5; q++) {
            float p = pg[l * (NQ - 1) + q];
            int ctrl = (tid >> q) & 1;
            float pc = ctrl ? p : 0.f;
            float qc = ctrl ? (1.f - p) : 1.f;
#pragma unroll 64
            for (int j = 0; j < 64; j++) {
                float f = __shfl_xor(a[j], 1 << (q + 1));
                a[j] = qc * a[j] + pc * f;
            }
        }
        // q = 5..8 : tgt = 6..9 wave bits (LDS exchange)
#pragma unroll 4
        for (int q = 5; q < 9; q++) {
            float p = pg[l * (NQ - 1) + q];
            int ctrl = (tid >> q) & 1;
            float pc = ctrl ? p : 0.f;
            float qc = ctrl ? (1.f - p) : 1.f;
            int partner = tid ^ (1 << (q + 1));
#pragma unroll 8
            for (int c = 0; c < 8; c++) {
                __syncthreads();
#pragma unroll 8
                for (int k = 0; k < 8; k++) lds[k * 1024 + tid] = a[c * 8 + k];
                __syncthreads();
#pragma unroll 8
                for (int k = 0; k < 8; k++) {
                    float f = lds[k * 1024 + partner];
                    a[c * 8 + k] = qc * a[c * 8 + k] + pc * f;
                }
            }
        }
        // q = 9 : ctrl wave bit 9, tgt register bit 0
        {
            float p = pg[l * (NQ - 1) + 9];
            int ctrl = (tid >> 9) & 1;
            float pc = ctrl ? p : 0.f;
            float qc = ctrl ? (1.f - p) : 1.f;
#pragma unroll 32
            for (int j = 0; j < 64; j += 2) {
                float a0 = a[j], a1 = a[j + 1];
                a[j]     = qc * a0 + pc * a1;
                a[j + 1] = qc * a1 + pc * a0;
            }
        }
        // q = 10..14 : ctrl and tgt both register bits
#pragma unroll 5
        for (int qq = 0; qq < 5; qq++) {
            float p = pg[l * (NQ - 1) + 10 + qq];
            float onem = 1.f - p;
            const int cmask = 1 << qq;
            const int tmask = 1 << (qq + 1);
#pragma unroll 64
            for (int j = 0; j < 64; j++) {
                if ((j & cmask) && !(j & tmask)) {
                    int j1 = j | tmask;
                    float a0 = a[j], a1 = a[j1];
                    a[j]  = onem * a0 + p * a1;
                    a[j1] = onem * a1 + p * a0;
                }
            }
        }
    }

    // ---------------- output: dense float32 real parts ----------------
    long long base = (long long)b * NSTATES;
#pragma unroll 64
    for (int j = 0; j < 64; j++) {
        long long fi = base + (long long)j * 1024 + tid;
        if (fi < out_floats) out[fi] = a[j];
    }
}

extern "C" void kernel_launch(void* const* d_in, const int* in_sizes, int n_in,
                              void* d_out, int out_size, void* d_ws, size_t ws_size,
                              hipStream_t stream) {
    const float* x   = (const float*)d_in[0];
    const float* rot = (const float*)d_in[1];
    const float* ent = (const float*)d_in[2];
    const float* W1  = (const float*)d_in[3];
    const float* b1  = (const float*)d_in[4];
    const float* W2  = (const float*)d_in[5];
    const float* b2  = (const float*)d_in[6];

    qsim<<<BATCH, 1024, 0, stream>>>(x, rot, ent, W1, b1, W2, b2,
                                     (float*)d_out, (long long)out_size,
                                     in_sizes[0], in_sizes[1], in_sizes[2],
                                     in_sizes[3], in_sizes[4], in_sizes[5],
                                     in_sizes[6]);
}

// Round 7
// 643.015 us; speedup vs baseline: 1.2366x; 1.2366x over previous
//
#include <hip/hip_runtime.h>
#include <math.h>

#define NQ 16
#define NLAYERS 3
#define NSTATES 65536   // 2^16
#define BATCH 256

// Clamped global read: any harness/size mismatch becomes a wrong value,
// never an OOB fault.
__device__ __forceinline__ float rd(const float* __restrict__ p, int i, int n) {
    return p[i < n ? i : (n - 1)];
}

// ---------------------------------------------------------------------------
// static_for: compile-time loop. Indices arrive as IC<I> tags, so every
// state-array subscript is a literal constant in the IR the frontend emits.
// This is what lets SROA fully scalarize the 64-float state array; plain
// "#pragma unroll" loops left runtime GEPs at SROA time and the array spilled
// to scratch (R4-R6: VGPR_Count=64, 3.3 GB HBM scratch traffic, ~790 us).
// ---------------------------------------------------------------------------
template <int I> struct IC { static constexpr int v = I; };

template <int I, int N, typename F>
__device__ __forceinline__ void sfor_i(F& f) {
    if constexpr (I < N) {
        f(IC<I>{});
        sfor_i<I + 1, N>(f);
    }
}
template <int N, typename F>
__device__ __forceinline__ void sfor(F&& f) { sfor_i<0, N>(f); }

// ---------------------------------------------------------------------------
// One block (1024 threads) per batch element. State index = j*1024 + tid
// (j = register index 0..63).
//   bits 0..5   = lane bits     -> __shfl_xor
//   bits 6..9   = wave bits     -> LDS exchange (32 KiB, 8 chunks of 8 regs)
//   bits 10..15 = register bits -> in-register butterflies
// waves_per_eu(4,4): 128-VGPR budget for the 64-float register state.
// Output: dense float32 REAL parts (imag==0; all gate matrices real).
// ---------------------------------------------------------------------------
__global__ __launch_bounds__(1024)
__attribute__((amdgpu_waves_per_eu(4, 4)))
void qsim(const float* __restrict__ x,
          const float* __restrict__ rot,
          const float* __restrict__ ent,
          const float* __restrict__ W1,
          const float* __restrict__ b1,
          const float* __restrict__ W2,
          const float* __restrict__ b2,
          float* __restrict__ out,
          long long out_floats,
          int nx, int nrot, int nent, int nW1, int nb1, int nW2, int nb2) {
    const int tid = threadIdx.x;
    const int b   = blockIdx.x;

    __shared__ float  lds[8 * 1024];           // 32 KiB exchange buffer
    __shared__ float4 Mg[NLAYERS * NQ];        // 48 gate matrices
    __shared__ float  pg[NLAYERS * (NQ - 1)];  // 45 CNOT mix probs
    __shared__ float  hidS[64];
    __shared__ float  hqS[16];

    // ---- Phase A: MLP hidden layer (64 threads) + sigmoid probs ----
    if (tid < 64) {
        float s = rd(b1, tid, nb1);
        for (int k = 0; k < 100; k++)
            s = fmaf(rd(x, b * 100 + k, nx), rd(W1, k * 64 + tid, nW1), s);
        hidS[tid] = fmaxf(s, 0.f);
    } else if (tid >= 64 && tid < 64 + NLAYERS * (NQ - 1)) {
        int i = tid - 64;
        pg[i] = 1.f / (1.f + expf(-rd(ent, i, nent)));
    }
    __syncthreads();

    // ---- Phase B: output layer hq (16 threads) ----
    if (tid < 16) {
        float s = rd(b2, tid, nb2);
#pragma unroll
        for (int i = 0; i < 64; i++)
            s = fmaf(hidS[i], rd(W2, i * 16 + tid, nW2), s);
        hqS[tid] = tanhf(s);
    }
    __syncthreads();

    // ---- Phase C: gate matrices (48 threads) ----
    if (tid < NLAYERS * NQ) {
        int q = tid & 15;
        float hv = hqS[q];
        float a0 = 0.5f * rd(rot, tid * 3 + 0, nrot) * hv;
        float a1 = 0.5f * rd(rot, tid * 3 + 1, nrot) * hv;
        float a2 = 0.5f * rd(rot, tid * 3 + 2, nrot) * hv;
        float cx = cosf(a0), sx = sinf(a0);
        float cy = cosf(a1), sy = sinf(a1);
        float cz = cosf(a2), sz = sinf(a2);
        Mg[tid] = make_float4(cx * cy * cz, -(sx * sy * sz),
                              sx * sy * cz,  cx * cy * sz);
    }
    __syncthreads();

    // ---- statevector init: |0...0> ----
    float a[64];
    sfor<64>([&](auto J) { a[J.v] = 0.f; });
    if (tid == 0) a[0] = 1.f;

    for (int l = 0; l < NLAYERS; l++) {
        // ---------------- single-qubit gates ----------------
        // q = 0..5 : lane bits (shfl; q never indexes a[])
#pragma unroll
        for (int q = 0; q < 6; q++) {
            float4 m = Mg[l * NQ + q];
            int bit = (tid >> q) & 1;
            float cown  = bit ? m.w : m.x;
            float cpart = bit ? m.z : m.y;
            sfor<64>([&](auto J) {
                float part = __shfl_xor(a[J.v], 1 << q);
                a[J.v] = cown * a[J.v] + cpart * part;
            });
        }
        // q = 6..9 : wave bits (LDS exchange, 8 chunks x 8 regs)
#pragma unroll
        for (int q = 6; q < 10; q++) {
            float4 m = Mg[l * NQ + q];
            int bit = (tid >> q) & 1;
            float cown  = bit ? m.w : m.x;
            float cpart = bit ? m.z : m.y;
            int partner = tid ^ (1 << q);
            sfor<8>([&](auto C) {
                __syncthreads();
                sfor<8>([&](auto K) {
                    lds[K.v * 1024 + tid] = a[C.v * 8 + K.v];
                });
                __syncthreads();
                sfor<8>([&](auto K) {
                    constexpr int idx = C.v * 8 + K.v;
                    float part = lds[K.v * 1024 + partner];
                    a[idx] = cown * a[idx] + cpart * part;
                });
            });
        }
        // q = 10..15 : register bits (in-register butterfly)
        sfor<6>([&](auto QQ) {
            float4 m = Mg[l * NQ + 10 + QQ.v];
            sfor<64>([&](auto J) {
                constexpr int h = 1 << QQ.v;
                if constexpr (!(J.v & h)) {
                    constexpr int j1 = J.v | h;
                    float a0 = a[J.v], a1 = a[j1];
                    a[J.v] = m.x * a0 + m.y * a1;
                    a[j1]  = m.z * a0 + m.w * a1;
                }
            });
        });

        // ---------------- noisy CNOTs: ctrl=q, tgt=q+1 ----------------
        // q = 0..4 : ctrl + tgt both lane bits (shfl on tgt)
#pragma unroll
        for (int q = 0; q < 5; q++) {
            float p = pg[l * (NQ - 1) + q];
            int ctrl = (tid >> q) & 1;
            float pc = ctrl ? p : 0.f;
            float qc = ctrl ? (1.f - p) : 1.f;
            sfor<64>([&](auto J) {
                float f = __shfl_xor(a[J.v], 1 << (q + 1));
                a[J.v] = qc * a[J.v] + pc * f;
            });
        }
        // q = 5..8 : tgt = 6..9 wave bits (LDS exchange)
#pragma unroll
        for (int q = 5; q < 9; q++) {
            float p = pg[l * (NQ - 1) + q];
            int ctrl = (tid >> q) & 1;
            float pc = ctrl ? p : 0.f;
            float qc = ctrl ? (1.f - p) : 1.f;
            int partner = tid ^ (1 << (q + 1));
            sfor<8>([&](auto C) {
                __syncthreads();
                sfor<8>([&](auto K) {
                    lds[K.v * 1024 + tid] = a[C.v * 8 + K.v];
                });
                __syncthreads();
                sfor<8>([&](auto K) {
                    constexpr int idx = C.v * 8 + K.v;
                    float f = lds[K.v * 1024 + partner];
                    a[idx] = qc * a[idx] + pc * f;
                });
            });
        }
        // q = 9 : ctrl wave bit 9, tgt register bit 0
        {
            float p = pg[l * (NQ - 1) + 9];
            int ctrl = (tid >> 9) & 1;
            float pc = ctrl ? p : 0.f;
            float qc = ctrl ? (1.f - p) : 1.f;
            sfor<32>([&](auto T) {
                constexpr int j = 2 * T.v;
                float a0 = a[j], a1 = a[j + 1];
                a[j]     = qc * a0 + pc * a1;
                a[j + 1] = qc * a1 + pc * a0;
            });
        }
        // q = 10..14 : ctrl and tgt both register bits
        sfor<5>([&](auto QQ) {
            float p = pg[l * (NQ - 1) + 10 + QQ.v];
            float onem = 1.f - p;
            sfor<64>([&](auto J) {
                constexpr int cmask = 1 << QQ.v;
                constexpr int tmask = 2 << QQ.v;
                if constexpr ((J.v & cmask) && !(J.v & tmask)) {
                    constexpr int j1 = J.v | tmask;
                    float a0 = a[J.v], a1 = a[j1];
                    a[J.v] = onem * a0 + p * a1;
                    a[j1]  = onem * a1 + p * a0;
                }
            });
        });
    }

    // ---------------- output: dense float32 real parts ----------------
    long long base = (long long)b * NSTATES;
    sfor<64>([&](auto J) {
        long long fi = base + (long long)(J.v * 1024) + tid;
        if (fi < out_floats) out[fi] = a[J.v];
    });
}

extern "C" void kernel_launch(void* const* d_in, const int* in_sizes, int n_in,
                              void* d_out, int out_size, void* d_ws, size_t ws_size,
                              hipStream_t stream) {
    const float* x   = (const float*)d_in[0];
    const float* rot = (const float*)d_in[1];
    const float* ent = (const float*)d_in[2];
    const float* W1  = (const float*)d_in[3];
    const float* b1  = (const float*)d_in[4];
    const float* W2  = (const float*)d_in[5];
    const float* b2  = (const float*)d_in[6];

    qsim<<<BATCH, 1024, 0, stream>>>(x, rot, ent, W1, b1, W2, b2,
                                     (float*)d_out, (long long)out_size,
                                     in_sizes[0], in_sizes[1], in_sizes[2],
                                     in_sizes[3], in_sizes[4], in_sizes[5],
                                     in_sizes[6]);
}